// Round 6
// baseline (133.929 us; speedup 1.0000x reference)
//
#include <hip/hip_runtime.h>
#include <hip/hip_bf16.h>

#define B_ 8
#define N_ 512

typedef __attribute__((ext_vector_type(8))) __bf16 bf16x8;
typedef __attribute__((ext_vector_type(8))) _Float16 f16x8;
typedef __attribute__((ext_vector_type(4))) _Float16 f16x4;
typedef __attribute__((ext_vector_type(2))) _Float16 h2;
typedef __attribute__((ext_vector_type(4))) float f32x4;
typedef __attribute__((ext_vector_type(4))) unsigned int u32x4;
typedef __attribute__((ext_vector_type(2))) unsigned int u32x2;

// pack two fp32 into bf16x2 by truncation: 1 v_perm_b32
__device__ __forceinline__ unsigned pk_bf16(float hi, float lo) {
    return __builtin_amdgcn_perm(__builtin_bit_cast(unsigned, hi),
                                 __builtin_bit_cast(unsigned, lo), 0x07060302u);
}

__device__ __forceinline__ h2 pkrtz(float a, float b) {
    return __builtin_bit_cast(h2, __builtin_amdgcn_cvt_pkrtz(a, b));
}
__device__ __forceinline__ unsigned pkrtz_u(float a, float b) {
    return __builtin_bit_cast(unsigned, __builtin_amdgcn_cvt_pkrtz(a, b));
}
// relu (pk_max_f16 vs 0) on a packed pair, returned as dword
__device__ __forceinline__ unsigned relu2_u(h2 v) {
    const h2 z2 = {(_Float16)0.0f, (_Float16)0.0f};
    return __builtin_bit_cast(unsigned, __builtin_elementwise_max(v, z2));
}

// ---------------- prep kernel: node MLP | w0t/w1t transpose | zero out ------
__global__ __launch_bounds__(256) void k_prep(
    const float* __restrict__ coords,
    const float* __restrict__ fw0, const float* __restrict__ fb0,
    const float* __restrict__ fw1, const float* __restrict__ fb1,
    const float* __restrict__ uw0, const float* __restrict__ uw1,
    __bf16* __restrict__ h_bf, __bf16* __restrict__ h_t,
    __bf16* __restrict__ w0t, __bf16* __restrict__ w1t,
    float* __restrict__ out, int out_size)
{
    const int blk = blockIdx.x;
    const int t = threadIdx.x;

    if (blk < 1024) {
        // ================= node MLP: 4 rows/block =================
        const int row0 = blk << 2;
        const int b = row0 >> 9;
        const int n0 = row0 & 511;
        __shared__ float cds4[4][4];
        __shared__ float hid4[4][64];
        if (t < 12) {
            int r = t / 3, d = t - 3 * r;
            cds4[r][d] = coords[(size_t)row0 * 3 + t];
        }
        __syncthreads();
        {
            int r = t >> 6, ch = t & 63;
            float v = fb0[ch];
            v += cds4[r][0] * fw0[0 * 64 + ch];
            v += cds4[r][1] * fw0[1 * 64 + ch];
            v += cds4[r][2] * fw0[2 * 64 + ch];
            hid4[r][ch] = fmaxf(v, 0.0f);
        }
        __syncthreads();
        {
            int ch = t & 127;
            int rp = (t >> 7) << 1;          // rows rp, rp+1
            float hv0 = fb1[ch], hv1 = hv0;
#pragma unroll 4
            for (int k = 0; k < 64; ++k) {
                float w = fw1[k * 128 + ch];
                hv0 += hid4[rp][k] * w;
                hv1 += hid4[rp + 1][k] * w;
            }
            hv0 = fmaxf(hv0, 0.0f);
            hv1 = fmaxf(hv1, 0.0f);
            h_bf[((size_t)(row0 + rp) << 7) + ch] = (__bf16)hv0;
            h_bf[((size_t)(row0 + rp + 1) << 7) + ch] = (__bf16)hv1;
            *(unsigned*)(h_t + (size_t)(b * 128 + ch) * 512 + n0 + rp) =
                pk_bf16(hv1, hv0);
        }
    } else if (blk < 1280) {
        // ---- w0t[c][k] = uw0[perm(k)][c]; coalesced read ----
        int k = blk - 1024;
        int c = t;
        int src = (k < 128) ? k : (k + 3);
        w0t[(size_t)c * 256 + k] = (__bf16)uw0[(size_t)src * 256 + c];
    } else if (blk < 1408) {
        // ---- w1t[c][k] = uw1[k][c]; coalesced read ----
        int id = (blk - 1280) * 256 + t;
        int c = id & 127, k = id >> 7;
        w1t[(size_t)c * 256 + k] = (__bf16)uw1[(size_t)k * 128 + c];
    } else {
        int i = (blk - 1408) * 256 + t;
        if (i < out_size) out[i] = 0.0f;
    }
}

// ---------------- fused kernel, 8-ROW tiles for 2 blocks/CU -----------------
// 512 blocks x 1024 thr (16 waves). Block owns 8 global rows. Phase 1: wave
// w -> (row w>>1, j-half w&1), 16 j-tiles each (half the serial chain of the
// 16-row version). LDS ~40 KB -> 2 blocks/CU co-resident: one block's
// aggregate/update phases overlap the other's adjacency phase. MFMA A-row
// duplication (m&7) keeps all verified fragment layouts; dup D-rows are not
// stored (maxpool is dup-safe since rows duplicate exactly).
#define AP 520
__global__ __launch_bounds__(1024) void k_fused(
    const float* __restrict__ coords,
    const float* __restrict__ aw0, const float* __restrict__ ab0,
    const float* __restrict__ aw1, const float* __restrict__ ab1,
    const float* __restrict__ aw2, const float* __restrict__ ab2,
    const __bf16* __restrict__ h_t, const __bf16* __restrict__ h_bf,
    const float* __restrict__ uw0, const float* __restrict__ ub0,
    const __bf16* __restrict__ w0t, const __bf16* __restrict__ w1t,
    const float* __restrict__ ub1,
    float* __restrict__ out)
{
    const int t = threadIdx.x;
    const int w = t >> 6;            // wave 0..15
    const int l = t & 63;
    const int q = l >> 4;
    const int m = l & 15;
    const int row0 = blockIdx.x << 3;   // 8 GLOBAL rows, same b
    const int b = row0 >> 9;

    __shared__ __align__(16) _Float16 s_aw1p[4096];      // 8 KB
    __shared__ __align__(16) float s_w[576];             // aw0|ab0|aw2|ab1
    __shared__ __align__(8) unsigned s_cj[512][2];       // 4 KB
    __shared__ __align__(16) __bf16 As[8][AP];           // 8.3 KB A-tile
    __shared__ __align__(16) __bf16 act[8][264];         // [row][k], k=[h|V]
    __shared__ __align__(16) __bf16 u1[8][264];
    __shared__ float vp[2][8][128];                      // 8 KB
    __shared__ float cds[8][4];

    // ================= staging (all 1024 threads) =================
    {
        // aw1: coalesced read (thread owns 4 consecutive floats), f16
        // scatter-store into fragment layout.
        f32x4 wv = *(const f32x4*)(aw1 + t * 4);
        const int R = t >> 4;
        const int C4 = (t & 15) << 2;
        const int s = R >> 5, qq = (R >> 3) & 3, j = R & 7;
        const int ct = C4 >> 4, mm0 = C4 & 15;
        const int base = s * 2048 + ct * 512 + qq * 128 + mm0 * 8 + j;
#pragma unroll
        for (int e = 0; e < 4; ++e)
            s_aw1p[base + e * 8] = (_Float16)wv[e];

        // aw0(384) | ab0(64) | aw2(64) | ab1(64) -> s_w[0..576)
        if (t < 144) {
            const int o = t * 4;
            f32x4 v;
            if (o < 384)      v = *(const f32x4*)(aw0 + o);
            else if (o < 448) v = *(const f32x4*)(ab0 + (o - 384));
            else if (o < 512) v = *(const f32x4*)(aw2 + (o - 448));
            else              v = *(const f32x4*)(ab1 + (o - 512));
            *(f32x4*)&s_w[o] = v;
        }

        // cj for all 512 j of batch b, packed f16 {c0,c1,c2,1}
        if (t < 512) {
            const float* cj = coords + ((size_t)b * N_ + t) * 3;
            s_cj[t][0] = pkrtz_u(cj[0], cj[1]);
            s_cj[t][1] = pkrtz_u(cj[2], 1.0f);

            // stage h part of act: 512 thr x 4B covers 8x128 bf16
            unsigned hv = *(const unsigned*)(h_bf + ((size_t)row0 << 7) + t * 2);
            *(unsigned*)&act[(t * 2) >> 7][(t * 2) & 127] = hv;
        }

        if (t < 24) {
            int r = t / 3, d = t - 3 * r;
            cds[r][d] = coords[(size_t)row0 * 3 + t];
        }
    }
    __syncthreads();

    // ========== phase 1: adjacency MLP, wave w -> (row w>>1, half w&1) ======
    {
        const int r8 = w >> 1;
        const int jh = w & 1;
        const float* cp = coords + (size_t)(row0 + r8) * 3;
        const float ci0 = cp[0], ci1 = cp[1], ci2 = cp[2];

        // layer-0 A-fragments (x16 shape, k=0..3 live), row-permuted so
        // D == layer-1 B layout: t4 row m -> ch = (m>>2)*8+(m&3)+{0,4,32,36}
        f16x4 a0f[4];
        {
            const int chb = ((m >> 2) << 3) + (m & 3);
            const int offs[4] = {0, 4, 32, 36};
#pragma unroll
            for (int t4 = 0; t4 < 4; ++t4) {
                const int ch = chb + offs[t4];
                float o = s_w[384 + ch] + ci0 * s_w[ch] + ci1 * s_w[64 + ch]
                                        + ci2 * s_w[128 + ch];
                u32x2 fr;
                fr[0] = (q == 0) ? pkrtz_u(s_w[192 + ch], s_w[256 + ch]) : 0u;
                fr[1] = (q == 0) ? pkrtz_u(s_w[320 + ch], o) : 0u;
                a0f[t4] = __builtin_bit_cast(f16x4, fr);
            }
        }

        // layer-2 reduction A-fragments, x32 dense (K=32 full)
        f16x8 ewf[2];
#pragma unroll
        for (int g = 0; g < 2; ++g) {
            const float* e0 = &s_w[448 + g * 32 + (q << 2)];
            const float* e1 = e0 + 16;
            u32x4 fr;
            fr[0] = pkrtz_u(e0[0], e0[1]);
            fr[1] = pkrtz_u(e0[2], e0[3]);
            fr[2] = pkrtz_u(e1[0], e1[1]);
            fr[3] = pkrtz_u(e1[2], e1[3]);
            ewf[g] = __builtin_bit_cast(f16x8, fr);
        }

        f16x8 bfr[2][4];
#pragma unroll
        for (int s = 0; s < 2; ++s)
#pragma unroll
            for (int ct = 0; ct < 4; ++ct)
                bfr[s][ct] = *(const f16x8*)&s_aw1p[s * 2048 + ct * 512 + q * 128 + m * 8];

        f32x4 ab1q[4];
#pragma unroll
        for (int ct = 0; ct < 4; ++ct)
            ab1q[ct] = *(const f32x4*)&s_w[512 + ct * 16 + (q << 2)];

        const float ab2s = ab2[0];
        const f32x4 pr0 = {ab2s, ab2s, ab2s, ab2s};
        const f32x4 zf = {0.f, 0.f, 0.f, 0.f};

#pragma unroll 1
        for (int tt = 0; tt < 16; ++tt) {
            f16x4 bj = __builtin_bit_cast(
                f16x4, *(const u32x2*)s_cj[jh * 256 + (tt << 4) + m]);

            // layer 0: 4 row-permuted x16 MFMAs (k=0..3 live)
            f32x4 d0 = __builtin_amdgcn_mfma_f32_16x16x16f16(a0f[0], bj, zf, 0, 0, 0);
            f32x4 d1 = __builtin_amdgcn_mfma_f32_16x16x16f16(a0f[1], bj, zf, 0, 0, 0);
            f32x4 d2 = __builtin_amdgcn_mfma_f32_16x16x16f16(a0f[2], bj, zf, 0, 0, 0);
            f32x4 d3 = __builtin_amdgcn_mfma_f32_16x16x16f16(a0f[3], bj, zf, 0, 0, 0);

            // relu + pack straight into layer-1 B-fragments
            u32x4 pa, pb;
            pa[0] = relu2_u(pkrtz(d0[0], d0[1]));
            pa[1] = relu2_u(pkrtz(d0[2], d0[3]));
            pa[2] = relu2_u(pkrtz(d1[0], d1[1]));
            pa[3] = relu2_u(pkrtz(d1[2], d1[3]));
            pb[0] = relu2_u(pkrtz(d2[0], d2[1]));
            pb[1] = relu2_u(pkrtz(d2[2], d2[3]));
            pb[2] = relu2_u(pkrtz(d3[0], d3[1]));
            pb[3] = relu2_u(pkrtz(d3[2], d3[3]));
            f16x8 a0 = __builtin_bit_cast(f16x8, pa);
            f16x8 a1 = __builtin_bit_cast(f16x8, pb);

            // layer 1 transposed MFMA (f16); ab1 folded into C
            f32x4 c0v = __builtin_amdgcn_mfma_f32_16x16x32_f16(bfr[0][0], a0, ab1q[0], 0, 0, 0);
            c0v = __builtin_amdgcn_mfma_f32_16x16x32_f16(bfr[1][0], a1, c0v, 0, 0, 0);
            f32x4 c1v = __builtin_amdgcn_mfma_f32_16x16x32_f16(bfr[0][1], a0, ab1q[1], 0, 0, 0);
            c1v = __builtin_amdgcn_mfma_f32_16x16x32_f16(bfr[1][1], a1, c1v, 0, 0, 0);
            f32x4 c2v = __builtin_amdgcn_mfma_f32_16x16x32_f16(bfr[0][2], a0, ab1q[2], 0, 0, 0);
            c2v = __builtin_amdgcn_mfma_f32_16x16x32_f16(bfr[1][2], a1, c2v, 0, 0, 0);
            f32x4 c3v = __builtin_amdgcn_mfma_f32_16x16x32_f16(bfr[0][3], a0, ab1q[3], 0, 0, 0);
            c3v = __builtin_amdgcn_mfma_f32_16x16x32_f16(bfr[1][3], a1, c3v, 0, 0, 0);

            // layer 2: relu + pack, K=32 repack -> 2 dense x32 MFMAs
            u32x4 B0, B1;
            B0[0] = relu2_u(pkrtz(c0v[0], c0v[1]));
            B0[1] = relu2_u(pkrtz(c0v[2], c0v[3]));
            B0[2] = relu2_u(pkrtz(c1v[0], c1v[1]));
            B0[3] = relu2_u(pkrtz(c1v[2], c1v[3]));
            B1[0] = relu2_u(pkrtz(c2v[0], c2v[1]));
            B1[1] = relu2_u(pkrtz(c2v[2], c2v[3]));
            B1[2] = relu2_u(pkrtz(c3v[0], c3v[1]));
            B1[3] = relu2_u(pkrtz(c3v[2], c3v[3]));

            f32x4 pr = __builtin_amdgcn_mfma_f32_16x16x32_f16(
                ewf[0], __builtin_bit_cast(f16x8, B0), pr0, 0, 0, 0);
            pr = __builtin_amdgcn_mfma_f32_16x16x32_f16(
                ewf[1], __builtin_bit_cast(f16x8, B1), pr, 0, 0, 0);

            if (l < 16)
                As[r8][jh * 256 + (tt << 4) + l] = (__bf16)fmaxf(pr[0], 0.0f);
        }
    }
    __syncthreads();

    // ================= phase 2: V = As @ h_t (K-split x2) =================
    const int gw = w & 7;            // n-tile
    const int ks = w >> 3;           // K-half
    {
        const __bf16* hp = h_t + ((size_t)b << 16) + (size_t)(gw * 16 + m) * 512
                           + ks * 256 + q * 8;
        const __bf16* Ar = &As[m & 7][ks * 256 + q * 8];   // rows 8-15 dup
        f32x4 acc = {0.f, 0.f, 0.f, 0.f};
#pragma unroll 4
        for (int kt = 0; kt < 8; ++kt) {
            bf16x8 av = *(const bf16x8*)(Ar + kt * 32);
            bf16x8 bv = *(const bf16x8*)(hp + kt * 32);
            acc = __builtin_amdgcn_mfma_f32_16x16x32_bf16(av, bv, acc, 0, 0, 0);
        }
        if (q < 2) {        // D rows 0..7 valid, 8..15 dup
#pragma unroll
            for (int r = 0; r < 4; ++r)
                vp[ks][q * 4 + r][gw * 16 + m] = acc[r];
        }
    }
    __syncthreads();

    // combine K-halves -> act V part (1024 thr x 1 value: 8x128)
    {
        int row = t >> 7, ch = t & 127;
        act[row][128 + ch] = (__bf16)(vp[0][row][ch] + vp[1][row][ch]);
    }
    __syncthreads();

    // ================= phase 3: update MLP + maxpool =================
    bf16x8 af[8];
#pragma unroll
    for (int ch = 0; ch < 8; ++ch)
        af[ch] = *(const bf16x8*)&act[m & 7][q * 8 + 32 * ch];   // rows dup
    {
        const int c = w * 16 + m;
        const float wx = uw0[128 * 256 + c];
        const float wy = uw0[129 * 256 + c];
        const float wz = uw0[130 * 256 + c];
        const float bias = ub0[c];
        f32x4 a1c;
#pragma unroll
        for (int r = 0; r < 4; ++r)
            a1c[r] = bias + cds[(q * 4 + r) & 7][0] * wx
                          + cds[(q * 4 + r) & 7][1] * wy
                          + cds[(q * 4 + r) & 7][2] * wz;
        const __bf16* wp = w0t + (size_t)c * 256 + q * 8;
#pragma unroll
        for (int ch = 0; ch < 8; ++ch) {
            bf16x8 bfr = *(const bf16x8*)(wp + 32 * ch);
            a1c = __builtin_amdgcn_mfma_f32_16x16x32_bf16(af[ch], bfr, a1c, 0, 0, 0);
        }
        if (q < 2) {        // rows 0..7 valid
#pragma unroll
            for (int r = 0; r < 4; ++r)
                u1[q * 4 + r][c] = (__bf16)fmaxf(a1c[r], 0.0f);
        }
    }
    __syncthreads();

    if (w < 8) {
        bf16x8 af2[8];
#pragma unroll
        for (int ch = 0; ch < 8; ++ch)
            af2[ch] = *(const bf16x8*)&u1[m & 7][q * 8 + 32 * ch];  // rows dup
        const int c = w * 16 + m;
        float bias = ub1[c];
        f32x4 a2c = {bias, bias, bias, bias};
        const __bf16* wp = w1t + (size_t)c * 256 + q * 8;
#pragma unroll
        for (int ch = 0; ch < 8; ++ch) {
            bf16x8 bfr = *(const bf16x8*)(wp + 32 * ch);
            a2c = __builtin_amdgcn_mfma_f32_16x16x32_bf16(af2[ch], bfr, a2c, 0, 0, 0);
        }
        // max over 16 D-rows = max over 8 valid rows (8..15 are exact dups)
        float mx = fmaxf(fmaxf(a2c[0], a2c[1]), fmaxf(a2c[2], a2c[3]));
        mx = fmaxf(mx, 0.0f);
        mx = fmaxf(mx, __shfl_xor(mx, 16, 64));
        mx = fmaxf(mx, __shfl_xor(mx, 32, 64));
        if (l < 16)
            atomicMax((int*)(out + ((size_t)b << 7) + c), __float_as_int(mx));
    }
}

extern "C" void kernel_launch(void* const* d_in, const int* in_sizes, int n_in,
                              void* d_out, int out_size, void* d_ws, size_t ws_size,
                              hipStream_t stream)
{
    const float* coords = (const float*)d_in[0];
    const float* fw0 = (const float*)d_in[1];
    const float* fb0 = (const float*)d_in[2];
    const float* fw1 = (const float*)d_in[3];
    const float* fb1 = (const float*)d_in[4];
    const float* aw0 = (const float*)d_in[5];
    const float* ab0 = (const float*)d_in[6];
    const float* aw1 = (const float*)d_in[7];
    const float* ab1 = (const float*)d_in[8];
    const float* aw2 = (const float*)d_in[9];
    const float* ab2 = (const float*)d_in[10];
    const float* uw0 = (const float*)d_in[11];
    const float* ub0 = (const float*)d_in[12];
    const float* uw1 = (const float*)d_in[13];
    const float* ub1 = (const float*)d_in[14];
    float* out = (float*)d_out;

    // workspace layout
    char* ws = (char*)d_ws;
    __bf16* h_t  = (__bf16*)(ws);                            // 1 MB
    __bf16* h_bf = (__bf16*)(ws + (1u << 20));               // 1 MB
    __bf16* w0t  = (__bf16*)(ws + (2u << 20));               // 128 KB
    __bf16* w1t  = (__bf16*)(ws + (2u << 20) + (128u << 10));// 64 KB

    k_prep<<<1412, 256, 0, stream>>>(coords, fw0, fb0, fw1, fb1, uw0, uw1,
                                     h_bf, h_t, w0t, w1t, out, out_size);
    k_fused<<<512, 1024, 0, stream>>>(coords, aw0, ab0, aw1, ab1, aw2, ab2,
                                      h_t, h_bf, uw0, ub0, w0t, w1t, ub1, out);
}

// Round 7
// 122.777 us; speedup vs baseline: 1.0908x; 1.0908x over previous
//
#include <hip/hip_runtime.h>
#include <hip/hip_bf16.h>

#define B_ 8
#define N_ 512

typedef __attribute__((ext_vector_type(8))) __bf16 bf16x8;
typedef __attribute__((ext_vector_type(8))) _Float16 f16x8;
typedef __attribute__((ext_vector_type(4))) _Float16 f16x4;
typedef __attribute__((ext_vector_type(2))) _Float16 h2;
typedef __attribute__((ext_vector_type(4))) float f32x4;
typedef __attribute__((ext_vector_type(4))) unsigned int u32x4;
typedef __attribute__((ext_vector_type(2))) unsigned int u32x2;

// pack two fp32 into bf16x2 by truncation: 1 v_perm_b32
__device__ __forceinline__ unsigned pk_bf16(float hi, float lo) {
    return __builtin_amdgcn_perm(__builtin_bit_cast(unsigned, hi),
                                 __builtin_bit_cast(unsigned, lo), 0x07060302u);
}

__device__ __forceinline__ h2 pkrtz(float a, float b) {
    return __builtin_bit_cast(h2, __builtin_amdgcn_cvt_pkrtz(a, b));
}
__device__ __forceinline__ unsigned pkrtz_u(float a, float b) {
    return __builtin_bit_cast(unsigned, __builtin_amdgcn_cvt_pkrtz(a, b));
}
// relu (pk_max_f16 vs 0) on a packed pair, returned as dword
__device__ __forceinline__ unsigned relu2_u(h2 v) {
    const h2 z2 = {(_Float16)0.0f, (_Float16)0.0f};
    return __builtin_bit_cast(unsigned, __builtin_elementwise_max(v, z2));
}

// ---------------- prep kernel: node MLP | w0t/w1t transpose | zero out ------
__global__ __launch_bounds__(256) void k_prep(
    const float* __restrict__ coords,
    const float* __restrict__ fw0, const float* __restrict__ fb0,
    const float* __restrict__ fw1, const float* __restrict__ fb1,
    const float* __restrict__ uw0, const float* __restrict__ uw1,
    __bf16* __restrict__ h_bf, __bf16* __restrict__ h_t,
    __bf16* __restrict__ w0t, __bf16* __restrict__ w1t,
    float* __restrict__ out, int out_size)
{
    const int blk = blockIdx.x;
    const int t = threadIdx.x;

    if (blk < 1024) {
        // ================= node MLP: 4 rows/block =================
        const int row0 = blk << 2;
        const int b = row0 >> 9;
        const int n0 = row0 & 511;
        __shared__ float cds4[4][4];
        __shared__ float hid4[4][64];
        if (t < 12) {
            int r = t / 3, d = t - 3 * r;
            cds4[r][d] = coords[(size_t)row0 * 3 + t];
        }
        __syncthreads();
        {
            int r = t >> 6, ch = t & 63;
            float v = fb0[ch];
            v += cds4[r][0] * fw0[0 * 64 + ch];
            v += cds4[r][1] * fw0[1 * 64 + ch];
            v += cds4[r][2] * fw0[2 * 64 + ch];
            hid4[r][ch] = fmaxf(v, 0.0f);
        }
        __syncthreads();
        {
            int ch = t & 127;
            int rp = (t >> 7) << 1;          // rows rp, rp+1
            float hv0 = fb1[ch], hv1 = hv0;
#pragma unroll 4
            for (int k = 0; k < 64; ++k) {
                float w = fw1[k * 128 + ch];
                hv0 += hid4[rp][k] * w;
                hv1 += hid4[rp + 1][k] * w;
            }
            hv0 = fmaxf(hv0, 0.0f);
            hv1 = fmaxf(hv1, 0.0f);
            h_bf[((size_t)(row0 + rp) << 7) + ch] = (__bf16)hv0;
            h_bf[((size_t)(row0 + rp + 1) << 7) + ch] = (__bf16)hv1;
            *(unsigned*)(h_t + (size_t)(b * 128 + ch) * 512 + n0 + rp) =
                pk_bf16(hv1, hv0);
        }
    } else if (blk < 1280) {
        // ---- w0t[c][k] = uw0[perm(k)][c]; coalesced read ----
        int k = blk - 1024;
        int c = t;
        int src = (k < 128) ? k : (k + 3);
        w0t[(size_t)c * 256 + k] = (__bf16)uw0[(size_t)src * 256 + c];
    } else if (blk < 1408) {
        // ---- w1t[c][k] = uw1[k][c]; coalesced read ----
        int id = (blk - 1280) * 256 + t;
        int c = id & 127, k = id >> 7;
        w1t[(size_t)c * 256 + k] = (__bf16)uw1[(size_t)k * 128 + c];
    } else {
        int i = (blk - 1408) * 256 + t;
        if (i < out_size) out[i] = 0.0f;
    }
}

// ---------------- fused kernel: adjacency MLP -> LDS A-tile -> V=A@h -> MLP -
// 256 blocks x 1024 thr (16 waves), 16-row tiles (round-5 structure, best
// measured). KEY FIX: __launch_bounds__(1024, 4) = 4 waves/EU = 1 block/CU
// -> 128-VGPR budget. Round-6 counters showed VGPR_Count=52: the compiler
// was allocating for high occupancy and spilling the phase-1 working set
// (bfr 32 VGPR + ab1q 16 + ewf 8 + accumulators) to scratch on every
// iteration — the invariant ~38-48 us floor across 5 structural variants.
// LDS (~64 KB) limits to 1 block/CU anyway, so occupancy is unchanged.
#define AP 520
__global__ __launch_bounds__(1024, 4) void k_fused(
    const float* __restrict__ coords,
    const float* __restrict__ aw0, const float* __restrict__ ab0,
    const float* __restrict__ aw1, const float* __restrict__ ab1,
    const float* __restrict__ aw2, const float* __restrict__ ab2,
    const __bf16* __restrict__ h_t, const __bf16* __restrict__ h_bf,
    const float* __restrict__ uw0, const float* __restrict__ ub0,
    const __bf16* __restrict__ w0t, const __bf16* __restrict__ w1t,
    const float* __restrict__ ub1,
    float* __restrict__ out)
{
    const int t = threadIdx.x;
    const int w = t >> 6;            // wave 0..15
    const int l = t & 63;
    const int q = l >> 4;
    const int m = l & 15;
    const int row0 = blockIdx.x << 4;   // 16 GLOBAL rows, same b
    const int b = row0 >> 9;

    __shared__ __align__(16) _Float16 s_aw1p[4096];      // 8 KB
    __shared__ __align__(16) float s_w[576];             // aw0|ab0|aw2|ab1
    __shared__ __align__(8) unsigned s_cj[512][2];       // 4 KB
    __shared__ __align__(16) __bf16 As[16][AP];          // 16.6 KB A-tile
    __shared__ __align__(16) __bf16 act[16][264];        // [row][k], k=[h|V]
    __shared__ __align__(16) __bf16 u1[16][264];
    __shared__ float vp[2][16][128];                     // 16 KB
    __shared__ float cds[16][4];

    // ================= staging (all 1024 threads) =================
    {
        // aw1: coalesced read (thread owns 4 consecutive floats), f16
        // scatter-store into fragment layout.
        f32x4 wv = *(const f32x4*)(aw1 + t * 4);
        const int R = t >> 4;
        const int C4 = (t & 15) << 2;
        const int s = R >> 5, qq = (R >> 3) & 3, j = R & 7;
        const int ct = C4 >> 4, mm0 = C4 & 15;
        const int base = s * 2048 + ct * 512 + qq * 128 + mm0 * 8 + j;
#pragma unroll
        for (int e = 0; e < 4; ++e)
            s_aw1p[base + e * 8] = (_Float16)wv[e];

        // aw0(384) | ab0(64) | aw2(64) | ab1(64) -> s_w[0..576)
        if (t < 144) {
            const int o = t * 4;
            f32x4 v;
            if (o < 384)      v = *(const f32x4*)(aw0 + o);
            else if (o < 448) v = *(const f32x4*)(ab0 + (o - 384));
            else if (o < 512) v = *(const f32x4*)(aw2 + (o - 448));
            else              v = *(const f32x4*)(ab1 + (o - 512));
            *(f32x4*)&s_w[o] = v;
        }

        // cj for all 512 j of batch b, packed f16 {c0,c1,c2,1}
        if (t < 512) {
            const float* cj = coords + ((size_t)b * N_ + t) * 3;
            s_cj[t][0] = pkrtz_u(cj[0], cj[1]);
            s_cj[t][1] = pkrtz_u(cj[2], 1.0f);
        }

        // stage h part of act: 1024 thr x 4B covers 16x128 bf16
        unsigned hv = *(const unsigned*)(h_bf + ((size_t)row0 << 7) + t * 2);
        *(unsigned*)&act[(t * 2) >> 7][(t * 2) & 127] = hv;

        if (t < 48) {
            int r = t / 3, d = t - 3 * r;
            cds[r][d] = coords[(size_t)row0 * 3 + t];
        }
    }
    __syncthreads();

    // ================= phase 1: adjacency MLP, wave w -> row w ==========
    {
        const float* cp = coords + (size_t)(row0 + w) * 3;
        const float ci0 = cp[0], ci1 = cp[1], ci2 = cp[2];

        // layer-0 A-fragments (x16 shape, k=0..3 live), row-permuted so
        // D == layer-1 B layout: t4 row m -> ch = (m>>2)*8+(m&3)+{0,4,32,36}
        f16x4 a0f[4];
        {
            const int chb = ((m >> 2) << 3) + (m & 3);
            const int offs[4] = {0, 4, 32, 36};
#pragma unroll
            for (int t4 = 0; t4 < 4; ++t4) {
                const int ch = chb + offs[t4];
                float o = s_w[384 + ch] + ci0 * s_w[ch] + ci1 * s_w[64 + ch]
                                        + ci2 * s_w[128 + ch];
                u32x2 fr;
                fr[0] = (q == 0) ? pkrtz_u(s_w[192 + ch], s_w[256 + ch]) : 0u;
                fr[1] = (q == 0) ? pkrtz_u(s_w[320 + ch], o) : 0u;
                a0f[t4] = __builtin_bit_cast(f16x4, fr);
            }
        }

        // layer-2 reduction A-fragments, x32 dense (K=32 full)
        f16x8 ewf[2];
#pragma unroll
        for (int g = 0; g < 2; ++g) {
            const float* e0 = &s_w[448 + g * 32 + (q << 2)];
            const float* e1 = e0 + 16;
            u32x4 fr;
            fr[0] = pkrtz_u(e0[0], e0[1]);
            fr[1] = pkrtz_u(e0[2], e0[3]);
            fr[2] = pkrtz_u(e1[0], e1[1]);
            fr[3] = pkrtz_u(e1[2], e1[3]);
            ewf[g] = __builtin_bit_cast(f16x8, fr);
        }

        f16x8 bfr[2][4];
#pragma unroll
        for (int s = 0; s < 2; ++s)
#pragma unroll
            for (int ct = 0; ct < 4; ++ct)
                bfr[s][ct] = *(const f16x8*)&s_aw1p[s * 2048 + ct * 512 + q * 128 + m * 8];

        f32x4 ab1q[4];
#pragma unroll
        for (int ct = 0; ct < 4; ++ct)
            ab1q[ct] = *(const f32x4*)&s_w[512 + ct * 16 + (q << 2)];

        const float ab2s = ab2[0];
        const f32x4 pr0 = {ab2s, ab2s, ab2s, ab2s};
        const f32x4 zf = {0.f, 0.f, 0.f, 0.f};

#pragma unroll 1
        for (int tt = 0; tt < 32; ++tt) {
            f16x4 bj = __builtin_bit_cast(f16x4, *(const u32x2*)s_cj[(tt << 4) + m]);

            // layer 0: 4 row-permuted x16 MFMAs (k=0..3 live)
            f32x4 d0 = __builtin_amdgcn_mfma_f32_16x16x16f16(a0f[0], bj, zf, 0, 0, 0);
            f32x4 d1 = __builtin_amdgcn_mfma_f32_16x16x16f16(a0f[1], bj, zf, 0, 0, 0);
            f32x4 d2 = __builtin_amdgcn_mfma_f32_16x16x16f16(a0f[2], bj, zf, 0, 0, 0);
            f32x4 d3 = __builtin_amdgcn_mfma_f32_16x16x16f16(a0f[3], bj, zf, 0, 0, 0);

            // relu + pack straight into layer-1 B-fragments
            u32x4 pa, pb;
            pa[0] = relu2_u(pkrtz(d0[0], d0[1]));
            pa[1] = relu2_u(pkrtz(d0[2], d0[3]));
            pa[2] = relu2_u(pkrtz(d1[0], d1[1]));
            pa[3] = relu2_u(pkrtz(d1[2], d1[3]));
            pb[0] = relu2_u(pkrtz(d2[0], d2[1]));
            pb[1] = relu2_u(pkrtz(d2[2], d2[3]));
            pb[2] = relu2_u(pkrtz(d3[0], d3[1]));
            pb[3] = relu2_u(pkrtz(d3[2], d3[3]));
            f16x8 a0 = __builtin_bit_cast(f16x8, pa);
            f16x8 a1 = __builtin_bit_cast(f16x8, pb);

            // layer 1 transposed MFMA (f16); ab1 folded into C
            f32x4 c0v = __builtin_amdgcn_mfma_f32_16x16x32_f16(bfr[0][0], a0, ab1q[0], 0, 0, 0);
            c0v = __builtin_amdgcn_mfma_f32_16x16x32_f16(bfr[1][0], a1, c0v, 0, 0, 0);
            f32x4 c1v = __builtin_amdgcn_mfma_f32_16x16x32_f16(bfr[0][1], a0, ab1q[1], 0, 0, 0);
            c1v = __builtin_amdgcn_mfma_f32_16x16x32_f16(bfr[1][1], a1, c1v, 0, 0, 0);
            f32x4 c2v = __builtin_amdgcn_mfma_f32_16x16x32_f16(bfr[0][2], a0, ab1q[2], 0, 0, 0);
            c2v = __builtin_amdgcn_mfma_f32_16x16x32_f16(bfr[1][2], a1, c2v, 0, 0, 0);
            f32x4 c3v = __builtin_amdgcn_mfma_f32_16x16x32_f16(bfr[0][3], a0, ab1q[3], 0, 0, 0);
            c3v = __builtin_amdgcn_mfma_f32_16x16x32_f16(bfr[1][3], a1, c3v, 0, 0, 0);

            // layer 2: relu + pack, K=32 repack -> 2 dense x32 MFMAs
            u32x4 B0, B1;
            B0[0] = relu2_u(pkrtz(c0v[0], c0v[1]));
            B0[1] = relu2_u(pkrtz(c0v[2], c0v[3]));
            B0[2] = relu2_u(pkrtz(c1v[0], c1v[1]));
            B0[3] = relu2_u(pkrtz(c1v[2], c1v[3]));
            B1[0] = relu2_u(pkrtz(c2v[0], c2v[1]));
            B1[1] = relu2_u(pkrtz(c2v[2], c2v[3]));
            B1[2] = relu2_u(pkrtz(c3v[0], c3v[1]));
            B1[3] = relu2_u(pkrtz(c3v[2], c3v[3]));

            f32x4 pr = __builtin_amdgcn_mfma_f32_16x16x32_f16(
                ewf[0], __builtin_bit_cast(f16x8, B0), pr0, 0, 0, 0);
            pr = __builtin_amdgcn_mfma_f32_16x16x32_f16(
                ewf[1], __builtin_bit_cast(f16x8, B1), pr, 0, 0, 0);

            if (l < 16) As[w][(tt << 4) + l] = (__bf16)fmaxf(pr[0], 0.0f);
        }
    }
    __syncthreads();

    // ================= phase 2: V = As @ h_t (K-split x2) =================
    const int gw = w & 7;            // n-tile
    const int ks = w >> 3;           // K-half
    {
        const __bf16* hp = h_t + ((size_t)b << 16) + (size_t)(gw * 16 + m) * 512
                           + ks * 256 + q * 8;
        const __bf16* Ar = &As[m][ks * 256 + q * 8];
        f32x4 acc = {0.f, 0.f, 0.f, 0.f};
#pragma unroll 4
        for (int kt = 0; kt < 8; ++kt) {
            bf16x8 av = *(const bf16x8*)(Ar + kt * 32);
            bf16x8 bv = *(const bf16x8*)(hp + kt * 32);
            acc = __builtin_amdgcn_mfma_f32_16x16x32_bf16(av, bv, acc, 0, 0, 0);
        }
#pragma unroll
        for (int r = 0; r < 4; ++r)
            vp[ks][q * 4 + r][gw * 16 + m] = acc[r];
    }
    __syncthreads();

    // combine K-halves -> act V part (1024 thr x 2 values)
#pragma unroll
    for (int it = 0; it < 2; ++it) {
        int idx = t + it * 1024;
        int row = idx >> 7, ch = idx & 127;
        act[row][128 + ch] = (__bf16)(vp[0][row][ch] + vp[1][row][ch]);
    }
    __syncthreads();

    // ================= phase 3: update MLP + maxpool =================
    bf16x8 af[8];
#pragma unroll
    for (int ch = 0; ch < 8; ++ch)
        af[ch] = *(const bf16x8*)&act[m][q * 8 + 32 * ch];
    {
        const int c = w * 16 + m;
        const float wx = uw0[128 * 256 + c];
        const float wy = uw0[129 * 256 + c];
        const float wz = uw0[130 * 256 + c];
        const float bias = ub0[c];
        f32x4 a1c;
#pragma unroll
        for (int r = 0; r < 4; ++r)
            a1c[r] = bias + cds[q * 4 + r][0] * wx + cds[q * 4 + r][1] * wy
                          + cds[q * 4 + r][2] * wz;
        const __bf16* wp = w0t + (size_t)c * 256 + q * 8;
#pragma unroll
        for (int ch = 0; ch < 8; ++ch) {
            bf16x8 bfr = *(const bf16x8*)(wp + 32 * ch);
            a1c = __builtin_amdgcn_mfma_f32_16x16x32_bf16(af[ch], bfr, a1c, 0, 0, 0);
        }
#pragma unroll
        for (int r = 0; r < 4; ++r)
            u1[q * 4 + r][c] = (__bf16)fmaxf(a1c[r], 0.0f);
    }
    __syncthreads();

    if (w < 8) {
        bf16x8 af2[8];
#pragma unroll
        for (int ch = 0; ch < 8; ++ch)
            af2[ch] = *(const bf16x8*)&u1[m][q * 8 + 32 * ch];
        const int c = w * 16 + m;
        float bias = ub1[c];
        f32x4 a2c = {bias, bias, bias, bias};
        const __bf16* wp = w1t + (size_t)c * 256 + q * 8;
#pragma unroll
        for (int ch = 0; ch < 8; ++ch) {
            bf16x8 bfr = *(const bf16x8*)(wp + 32 * ch);
            a2c = __builtin_amdgcn_mfma_f32_16x16x32_bf16(af2[ch], bfr, a2c, 0, 0, 0);
        }
        float mx = fmaxf(fmaxf(a2c[0], a2c[1]), fmaxf(a2c[2], a2c[3]));
        mx = fmaxf(mx, 0.0f);
        mx = fmaxf(mx, __shfl_xor(mx, 16, 64));
        mx = fmaxf(mx, __shfl_xor(mx, 32, 64));
        if (l < 16)
            atomicMax((int*)(out + ((size_t)b << 7) + c), __float_as_int(mx));
    }
}

extern "C" void kernel_launch(void* const* d_in, const int* in_sizes, int n_in,
                              void* d_out, int out_size, void* d_ws, size_t ws_size,
                              hipStream_t stream)
{
    const float* coords = (const float*)d_in[0];
    const float* fw0 = (const float*)d_in[1];
    const float* fb0 = (const float*)d_in[2];
    const float* fw1 = (const float*)d_in[3];
    const float* fb1 = (const float*)d_in[4];
    const float* aw0 = (const float*)d_in[5];
    const float* ab0 = (const float*)d_in[6];
    const float* aw1 = (const float*)d_in[7];
    const float* ab1 = (const float*)d_in[8];
    const float* aw2 = (const float*)d_in[9];
    const float* ab2 = (const float*)d_in[10];
    const float* uw0 = (const float*)d_in[11];
    const float* ub0 = (const float*)d_in[12];
    const float* uw1 = (const float*)d_in[13];
    const float* ub1 = (const float*)d_in[14];
    float* out = (float*)d_out;

    // workspace layout
    char* ws = (char*)d_ws;
    __bf16* h_t  = (__bf16*)(ws);                            // 1 MB
    __bf16* h_bf = (__bf16*)(ws + (1u << 20));               // 1 MB
    __bf16* w0t  = (__bf16*)(ws + (2u << 20));               // 128 KB
    __bf16* w1t  = (__bf16*)(ws + (2u << 20) + (128u << 10));// 64 KB

    k_prep<<<1412, 256, 0, stream>>>(coords, fw0, fb0, fw1, fb1, uw0, uw1,
                                     h_bf, h_t, w0t, w1t, out, out_size);
    k_fused<<<256, 1024, 0, stream>>>(coords, aw0, ab0, aw1, ab1, aw2, ab2,
                                      h_t, h_bf, uw0, ub0, w0t, w1t, ub1, out);
}

// Round 9
// 120.816 us; speedup vs baseline: 1.1085x; 1.0162x over previous
//
#include <hip/hip_runtime.h>
#include <hip/hip_bf16.h>

#define B_ 8
#define N_ 512

typedef __attribute__((ext_vector_type(8))) __bf16 bf16x8;
typedef __attribute__((ext_vector_type(8))) _Float16 f16x8;
typedef __attribute__((ext_vector_type(4))) _Float16 f16x4;
typedef __attribute__((ext_vector_type(2))) _Float16 h2;
typedef __attribute__((ext_vector_type(4))) float f32x4;
typedef __attribute__((ext_vector_type(4))) unsigned int u32x4;
typedef __attribute__((ext_vector_type(2))) unsigned int u32x2;

// pack two fp32 into bf16x2 by truncation: 1 v_perm_b32
__device__ __forceinline__ unsigned pk_bf16(float hi, float lo) {
    return __builtin_amdgcn_perm(__builtin_bit_cast(unsigned, hi),
                                 __builtin_bit_cast(unsigned, lo), 0x07060302u);
}

__device__ __forceinline__ h2 pkrtz(float a, float b) {
    return __builtin_bit_cast(h2, __builtin_amdgcn_cvt_pkrtz(a, b));
}
__device__ __forceinline__ unsigned pkrtz_u(float a, float b) {
    return __builtin_bit_cast(unsigned, __builtin_amdgcn_cvt_pkrtz(a, b));
}
// relu (pk_max_f16 vs 0) on a packed pair, returned as dword
__device__ __forceinline__ unsigned relu2_u(h2 v) {
    const h2 z2 = {(_Float16)0.0f, (_Float16)0.0f};
    return __builtin_bit_cast(unsigned, __builtin_elementwise_max(v, z2));
}

// ---------------- prep kernel: node MLP | w0t/w1t transpose | zero out ------
__global__ __launch_bounds__(256) void k_prep(
    const float* __restrict__ coords,
    const float* __restrict__ fw0, const float* __restrict__ fb0,
    const float* __restrict__ fw1, const float* __restrict__ fb1,
    const float* __restrict__ uw0, const float* __restrict__ uw1,
    __bf16* __restrict__ h_bf, __bf16* __restrict__ h_t,
    __bf16* __restrict__ w0t, __bf16* __restrict__ w1t,
    float* __restrict__ out, int out_size)
{
    const int blk = blockIdx.x;
    const int t = threadIdx.x;

    if (blk < 1024) {
        // ================= node MLP: 4 rows/block =================
        const int row0 = blk << 2;
        const int b = row0 >> 9;
        const int n0 = row0 & 511;
        __shared__ float cds4[4][4];
        __shared__ float hid4[4][64];
        if (t < 12) {
            int r = t / 3, d = t - 3 * r;
            cds4[r][d] = coords[(size_t)row0 * 3 + t];
        }
        __syncthreads();
        {
            int r = t >> 6, ch = t & 63;
            float v = fb0[ch];
            v += cds4[r][0] * fw0[0 * 64 + ch];
            v += cds4[r][1] * fw0[1 * 64 + ch];
            v += cds4[r][2] * fw0[2 * 64 + ch];
            hid4[r][ch] = fmaxf(v, 0.0f);
        }
        __syncthreads();
        {
            int ch = t & 127;
            int rp = (t >> 7) << 1;          // rows rp, rp+1
            float hv0 = fb1[ch], hv1 = hv0;
#pragma unroll 4
            for (int k = 0; k < 64; ++k) {
                float w = fw1[k * 128 + ch];
                hv0 += hid4[rp][k] * w;
                hv1 += hid4[rp + 1][k] * w;
            }
            hv0 = fmaxf(hv0, 0.0f);
            hv1 = fmaxf(hv1, 0.0f);
            h_bf[((size_t)(row0 + rp) << 7) + ch] = (__bf16)hv0;
            h_bf[((size_t)(row0 + rp + 1) << 7) + ch] = (__bf16)hv1;
            *(unsigned*)(h_t + (size_t)(b * 128 + ch) * 512 + n0 + rp) =
                pk_bf16(hv1, hv0);
        }
    } else if (blk < 1280) {
        // ---- w0t[c][k] = uw0[perm(k)][c]; coalesced read ----
        int k = blk - 1024;
        int c = t;
        int src = (k < 128) ? k : (k + 3);
        w0t[(size_t)c * 256 + k] = (__bf16)uw0[(size_t)src * 256 + c];
    } else if (blk < 1408) {
        // ---- w1t[c][k] = uw1[k][c]; coalesced read ----
        int id = (blk - 1280) * 256 + t;
        int c = id & 127, k = id >> 7;
        w1t[(size_t)c * 256 + k] = (__bf16)uw1[(size_t)k * 128 + c];
    } else {
        int i = (blk - 1408) * 256 + t;
        if (i < out_size) out[i] = 0.0f;
    }
}

// ---------------- fused kernel: adjacency MLP -> LDS A-tile -> V=A@h -> MLP -
// 256 blocks x 1024 thr (16 waves), 16-row tiles. VERIFIED round-5/7
// structure (122.4/122.8 us, passed twice). Round-8's u_j-hoist variant
// failed tolerance (absmax 38.5) — reverted. Session conclusion: the
// remaining controllable time (~37 us of our two kernels) sits under a
// ~85 us harness floor (41 us re-poison fill + reset dispatches + gaps);
// scheduling-level levers (ILP, shapes, occupancy, launch bounds,
// prologue coalescing) were all measured neutral.
#define AP 520
__global__ __launch_bounds__(1024, 4) void k_fused(
    const float* __restrict__ coords,
    const float* __restrict__ aw0, const float* __restrict__ ab0,
    const float* __restrict__ aw1, const float* __restrict__ ab1,
    const float* __restrict__ aw2, const float* __restrict__ ab2,
    const __bf16* __restrict__ h_t, const __bf16* __restrict__ h_bf,
    const float* __restrict__ uw0, const float* __restrict__ ub0,
    const __bf16* __restrict__ w0t, const __bf16* __restrict__ w1t,
    const float* __restrict__ ub1,
    float* __restrict__ out)
{
    const int t = threadIdx.x;
    const int w = t >> 6;            // wave 0..15
    const int l = t & 63;
    const int q = l >> 4;
    const int m = l & 15;
    const int row0 = blockIdx.x << 4;   // 16 GLOBAL rows, same b
    const int b = row0 >> 9;

    __shared__ __align__(16) _Float16 s_aw1p[4096];      // 8 KB
    __shared__ __align__(16) float s_w[576];             // aw0|ab0|aw2|ab1
    __shared__ __align__(8) unsigned s_cj[512][2];       // 4 KB
    __shared__ __align__(16) __bf16 As[16][AP];          // 16.6 KB A-tile
    __shared__ __align__(16) __bf16 act[16][264];        // [row][k], k=[h|V]
    __shared__ __align__(16) __bf16 u1[16][264];
    __shared__ float vp[2][16][128];                     // 16 KB
    __shared__ float cds[16][4];

    // ================= staging (all 1024 threads) =================
    {
        // aw1: coalesced read (thread owns 4 consecutive floats), f16
        // scatter-store into fragment layout.
        f32x4 wv = *(const f32x4*)(aw1 + t * 4);
        const int R = t >> 4;
        const int C4 = (t & 15) << 2;
        const int s = R >> 5, qq = (R >> 3) & 3, j = R & 7;
        const int ct = C4 >> 4, mm0 = C4 & 15;
        const int base = s * 2048 + ct * 512 + qq * 128 + mm0 * 8 + j;
#pragma unroll
        for (int e = 0; e < 4; ++e)
            s_aw1p[base + e * 8] = (_Float16)wv[e];

        // aw0(384) | ab0(64) | aw2(64) | ab1(64) -> s_w[0..576)
        if (t < 144) {
            const int o = t * 4;
            f32x4 v;
            if (o < 384)      v = *(const f32x4*)(aw0 + o);
            else if (o < 448) v = *(const f32x4*)(ab0 + (o - 384));
            else if (o < 512) v = *(const f32x4*)(aw2 + (o - 448));
            else              v = *(const f32x4*)(ab1 + (o - 512));
            *(f32x4*)&s_w[o] = v;
        }

        // cj for all 512 j of batch b, packed f16 {c0,c1,c2,1}
        if (t < 512) {
            const float* cj = coords + ((size_t)b * N_ + t) * 3;
            s_cj[t][0] = pkrtz_u(cj[0], cj[1]);
            s_cj[t][1] = pkrtz_u(cj[2], 1.0f);
        }

        // stage h part of act: 1024 thr x 4B covers 16x128 bf16
        unsigned hv = *(const unsigned*)(h_bf + ((size_t)row0 << 7) + t * 2);
        *(unsigned*)&act[(t * 2) >> 7][(t * 2) & 127] = hv;

        if (t < 48) {
            int r = t / 3, d = t - 3 * r;
            cds[r][d] = coords[(size_t)row0 * 3 + t];
        }
    }
    __syncthreads();

    // ================= phase 1: adjacency MLP, wave w -> row w ==========
    {
        const float* cp = coords + (size_t)(row0 + w) * 3;
        const float ci0 = cp[0], ci1 = cp[1], ci2 = cp[2];

        // layer-0 A-fragments (x16 shape, k=0..3 live), row-permuted so
        // D == layer-1 B layout: t4 row m -> ch = (m>>2)*8+(m&3)+{0,4,32,36}
        f16x4 a0f[4];
        {
            const int chb = ((m >> 2) << 3) + (m & 3);
            const int offs[4] = {0, 4, 32, 36};
#pragma unroll
            for (int t4 = 0; t4 < 4; ++t4) {
                const int ch = chb + offs[t4];
                float o = s_w[384 + ch] + ci0 * s_w[ch] + ci1 * s_w[64 + ch]
                                        + ci2 * s_w[128 + ch];
                u32x2 fr;
                fr[0] = (q == 0) ? pkrtz_u(s_w[192 + ch], s_w[256 + ch]) : 0u;
                fr[1] = (q == 0) ? pkrtz_u(s_w[320 + ch], o) : 0u;
                a0f[t4] = __builtin_bit_cast(f16x4, fr);
            }
        }

        // layer-2 reduction A-fragments, x32 dense (K=32 full)
        f16x8 ewf[2];
#pragma unroll
        for (int g = 0; g < 2; ++g) {
            const float* e0 = &s_w[448 + g * 32 + (q << 2)];
            const float* e1 = e0 + 16;
            u32x4 fr;
            fr[0] = pkrtz_u(e0[0], e0[1]);
            fr[1] = pkrtz_u(e0[2], e0[3]);
            fr[2] = pkrtz_u(e1[0], e1[1]);
            fr[3] = pkrtz_u(e1[2], e1[3]);
            ewf[g] = __builtin_bit_cast(f16x8, fr);
        }

        f16x8 bfr[2][4];
#pragma unroll
        for (int s = 0; s < 2; ++s)
#pragma unroll
            for (int ct = 0; ct < 4; ++ct)
                bfr[s][ct] = *(const f16x8*)&s_aw1p[s * 2048 + ct * 512 + q * 128 + m * 8];

        f32x4 ab1q[4];
#pragma unroll
        for (int ct = 0; ct < 4; ++ct)
            ab1q[ct] = *(const f32x4*)&s_w[512 + ct * 16 + (q << 2)];

        const float ab2s = ab2[0];
        const f32x4 pr0 = {ab2s, ab2s, ab2s, ab2s};
        const f32x4 zf = {0.f, 0.f, 0.f, 0.f};

#pragma unroll 1
        for (int tt = 0; tt < 32; ++tt) {
            f16x4 bj = __builtin_bit_cast(f16x4, *(const u32x2*)s_cj[(tt << 4) + m]);

            // layer 0: 4 row-permuted x16 MFMAs (k=0..3 live)
            f32x4 d0 = __builtin_amdgcn_mfma_f32_16x16x16f16(a0f[0], bj, zf, 0, 0, 0);
            f32x4 d1 = __builtin_amdgcn_mfma_f32_16x16x16f16(a0f[1], bj, zf, 0, 0, 0);
            f32x4 d2 = __builtin_amdgcn_mfma_f32_16x16x16f16(a0f[2], bj, zf, 0, 0, 0);
            f32x4 d3 = __builtin_amdgcn_mfma_f32_16x16x16f16(a0f[3], bj, zf, 0, 0, 0);

            // relu + pack straight into layer-1 B-fragments
            u32x4 pa, pb;
            pa[0] = relu2_u(pkrtz(d0[0], d0[1]));
            pa[1] = relu2_u(pkrtz(d0[2], d0[3]));
            pa[2] = relu2_u(pkrtz(d1[0], d1[1]));
            pa[3] = relu2_u(pkrtz(d1[2], d1[3]));
            pb[0] = relu2_u(pkrtz(d2[0], d2[1]));
            pb[1] = relu2_u(pkrtz(d2[2], d2[3]));
            pb[2] = relu2_u(pkrtz(d3[0], d3[1]));
            pb[3] = relu2_u(pkrtz(d3[2], d3[3]));
            f16x8 a0 = __builtin_bit_cast(f16x8, pa);
            f16x8 a1 = __builtin_bit_cast(f16x8, pb);

            // layer 1 transposed MFMA (f16); ab1 folded into C
            f32x4 c0v = __builtin_amdgcn_mfma_f32_16x16x32_f16(bfr[0][0], a0, ab1q[0], 0, 0, 0);
            c0v = __builtin_amdgcn_mfma_f32_16x16x32_f16(bfr[1][0], a1, c0v, 0, 0, 0);
            f32x4 c1v = __builtin_amdgcn_mfma_f32_16x16x32_f16(bfr[0][1], a0, ab1q[1], 0, 0, 0);
            c1v = __builtin_amdgcn_mfma_f32_16x16x32_f16(bfr[1][1], a1, c1v, 0, 0, 0);
            f32x4 c2v = __builtin_amdgcn_mfma_f32_16x16x32_f16(bfr[0][2], a0, ab1q[2], 0, 0, 0);
            c2v = __builtin_amdgcn_mfma_f32_16x16x32_f16(bfr[1][2], a1, c2v, 0, 0, 0);
            f32x4 c3v = __builtin_amdgcn_mfma_f32_16x16x32_f16(bfr[0][3], a0, ab1q[3], 0, 0, 0);
            c3v = __builtin_amdgcn_mfma_f32_16x16x32_f16(bfr[1][3], a1, c3v, 0, 0, 0);

            // layer 2: relu + pack, K=32 repack -> 2 dense x32 MFMAs
            u32x4 B0, B1;
            B0[0] = relu2_u(pkrtz(c0v[0], c0v[1]));
            B0[1] = relu2_u(pkrtz(c0v[2], c0v[3]));
            B0[2] = relu2_u(pkrtz(c1v[0], c1v[1]));
            B0[3] = relu2_u(pkrtz(c1v[2], c1v[3]));
            B1[0] = relu2_u(pkrtz(c2v[0], c2v[1]));
            B1[1] = relu2_u(pkrtz(c2v[2], c2v[3]));
            B1[2] = relu2_u(pkrtz(c3v[0], c3v[1]));
            B1[3] = relu2_u(pkrtz(c3v[2], c3v[3]));

            f32x4 pr = __builtin_amdgcn_mfma_f32_16x16x32_f16(
                ewf[0], __builtin_bit_cast(f16x8, B0), pr0, 0, 0, 0);
            pr = __builtin_amdgcn_mfma_f32_16x16x32_f16(
                ewf[1], __builtin_bit_cast(f16x8, B1), pr, 0, 0, 0);

            if (l < 16) As[w][(tt << 4) + l] = (__bf16)fmaxf(pr[0], 0.0f);
        }
    }
    __syncthreads();

    // ================= phase 2: V = As @ h_t (K-split x2) =================
    const int gw = w & 7;            // n-tile
    const int ks = w >> 3;           // K-half
    {
        const __bf16* hp = h_t + ((size_t)b << 16) + (size_t)(gw * 16 + m) * 512
                           + ks * 256 + q * 8;
        const __bf16* Ar = &As[m][ks * 256 + q * 8];
        f32x4 acc = {0.f, 0.f, 0.f, 0.f};
#pragma unroll 4
        for (int kt = 0; kt < 8; ++kt) {
            bf16x8 av = *(const bf16x8*)(Ar + kt * 32);
            bf16x8 bv = *(const bf16x8*)(hp + kt * 32);
            acc = __builtin_amdgcn_mfma_f32_16x16x32_bf16(av, bv, acc, 0, 0, 0);
        }
#pragma unroll
        for (int r = 0; r < 4; ++r)
            vp[ks][q * 4 + r][gw * 16 + m] = acc[r];
    }
    __syncthreads();

    // combine K-halves -> act V part (1024 thr x 2 values)
#pragma unroll
    for (int it = 0; it < 2; ++it) {
        int idx = t + it * 1024;
        int row = idx >> 7, ch = idx & 127;
        act[row][128 + ch] = (__bf16)(vp[0][row][ch] + vp[1][row][ch]);
    }
    __syncthreads();

    // ================= phase 3: update MLP + maxpool =================
    bf16x8 af[8];
#pragma unroll
    for (int ch = 0; ch < 8; ++ch)
        af[ch] = *(const bf16x8*)&act[m][q * 8 + 32 * ch];
    {
        const int c = w * 16 + m;
        const float wx = uw0[128 * 256 + c];
        const float wy = uw0[129 * 256 + c];
        const float wz = uw0[130 * 256 + c];
        const float bias = ub0[c];
        f32x4 a1c;
#pragma unroll
        for (int r = 0; r < 4; ++r)
            a1c[r] = bias + cds[q * 4 + r][0] * wx + cds[q * 4 + r][1] * wy
                          + cds[q * 4 + r][2] * wz;
        const __bf16* wp = w0t + (size_t)c * 256 + q * 8;
#pragma unroll
        for (int ch = 0; ch < 8; ++ch) {
            bf16x8 bfr = *(const bf16x8*)(wp + 32 * ch);
            a1c = __builtin_amdgcn_mfma_f32_16x16x32_bf16(af[ch], bfr, a1c, 0, 0, 0);
        }
#pragma unroll
        for (int r = 0; r < 4; ++r)
            u1[q * 4 + r][c] = (__bf16)fmaxf(a1c[r], 0.0f);
    }
    __syncthreads();

    if (w < 8) {
        bf16x8 af2[8];
#pragma unroll
        for (int ch = 0; ch < 8; ++ch)
            af2[ch] = *(const bf16x8*)&u1[m][q * 8 + 32 * ch];
        const int c = w * 16 + m;
        float bias = ub1[c];
        f32x4 a2c = {bias, bias, bias, bias};
        const __bf16* wp = w1t + (size_t)c * 256 + q * 8;
#pragma unroll
        for (int ch = 0; ch < 8; ++ch) {
            bf16x8 bfr = *(const bf16x8*)(wp + 32 * ch);
            a2c = __builtin_amdgcn_mfma_f32_16x16x32_bf16(af2[ch], bfr, a2c, 0, 0, 0);
        }
        float mx = fmaxf(fmaxf(a2c[0], a2c[1]), fmaxf(a2c[2], a2c[3]));
        mx = fmaxf(mx, 0.0f);
        mx = fmaxf(mx, __shfl_xor(mx, 16, 64));
        mx = fmaxf(mx, __shfl_xor(mx, 32, 64));
        if (l < 16)
            atomicMax((int*)(out + ((size_t)b << 7) + c), __float_as_int(mx));
    }
}

extern "C" void kernel_launch(void* const* d_in, const int* in_sizes, int n_in,
                              void* d_out, int out_size, void* d_ws, size_t ws_size,
                              hipStream_t stream)
{
    const float* coords = (const float*)d_in[0];
    const float* fw0 = (const float*)d_in[1];
    const float* fb0 = (const float*)d_in[2];
    const float* fw1 = (const float*)d_in[3];
    const float* fb1 = (const float*)d_in[4];
    const float* aw0 = (const float*)d_in[5];
    const float* ab0 = (const float*)d_in[6];
    const float* aw1 = (const float*)d_in[7];
    const float* ab1 = (const float*)d_in[8];
    const float* aw2 = (const float*)d_in[9];
    const float* ab2 = (const float*)d_in[10];
    const float* uw0 = (const float*)d_in[11];
    const float* ub0 = (const float*)d_in[12];
    const float* uw1 = (const float*)d_in[13];
    const float* ub1 = (const float*)d_in[14];
    float* out = (float*)d_out;

    // workspace layout
    char* ws = (char*)d_ws;
    __bf16* h_t  = (__bf16*)(ws);                            // 1 MB
    __bf16* h_bf = (__bf16*)(ws + (1u << 20));               // 1 MB
    __bf16* w0t  = (__bf16*)(ws + (2u << 20));               // 128 KB
    __bf16* w1t  = (__bf16*)(ws + (2u << 20) + (128u << 10));// 64 KB

    k_prep<<<1412, 256, 0, stream>>>(coords, fw0, fb0, fw1, fb1, uw0, uw1,
                                     h_bf, h_t, w0t, w1t, out, out_size);
    k_fused<<<256, 1024, 0, stream>>>(coords, aw0, ab0, aw1, ab1, aw2, ab2,
                                      h_t, h_bf, uw0, ub0, w0t, w1t, ub1, out);
}